// Round 2
// baseline (2181.388 us; speedup 1.0000x reference)
//
#include <hip/hip_runtime.h>
#include <hip/hip_bf16.h>

// Transformer block for MI355X. Round 2: f32 inputs/output (per reference),
// bf16 internal activations, f32 residual trunk. VALU baseline (MFMA next).

typedef __hip_bfloat16 bf16;

__device__ __forceinline__ float bits2f(unsigned short u) {
  union { unsigned int i; float f; } c; c.i = ((unsigned int)u) << 16; return c.f;
}
__device__ __forceinline__ unsigned short f2bits(float f) {
  bf16 b = __float2bfloat16(f);
  union { bf16 b; unsigned short u; } c; c.b = b; return c.u;
}

// ---------------- RMSNorm: f32 in, f32 gamma, bf16 out ----------------
__global__ __launch_bounds__(256) void rmsnorm_k(const float* __restrict__ x,
                                                 const float* __restrict__ g,
                                                 unsigned short* __restrict__ out)
{
  const int row = blockIdx.x, tid = threadIdx.x;
  const size_t rb = (size_t)row * 1024;
  float4 xv = *(const float4*)(x + rb + tid * 4);
  float v[4] = {xv.x, xv.y, xv.z, xv.w};
  float s = v[0]*v[0] + v[1]*v[1] + v[2]*v[2] + v[3]*v[3];
  #pragma unroll
  for (int off = 32; off > 0; off >>= 1) s += __shfl_down(s, off, 64);
  __shared__ float part[4];
  if ((tid & 63) == 0) part[tid >> 6] = s;
  __syncthreads();
  const float tot = part[0] + part[1] + part[2] + part[3];
  const float sc = rsqrtf(tot * (1.0f / 1024.0f) + 1.1920929e-07f);
  float4 gv = *(const float4*)(g + tid * 4);
  ushort4 o4 = { f2bits(v[0] * sc * gv.x), f2bits(v[1] * sc * gv.y),
                 f2bits(v[2] * sc * gv.z), f2bits(v[3] * sc * gv.w) };
  *(ushort4*)(out + rb + tid * 4) = o4;
}

// ---------------- GEMM: C = A[M,K](bf16) @ B[K,N](f32) + bias(f32) ----------------
// EPI 0: -> bf16 out                 (qkv)
// EPI 1: + f32 resid -> f32 out      (x1 = x + proj)
// EPI 2: GELU(exact) -> bf16 out     (fc1)
// EPI 3: + f32 resid -> f32 out      (final output)
template<int EPI>
__global__ __launch_bounds__(256) void gemm_k(
    const unsigned short* __restrict__ A,
    const float* __restrict__ B,
    const float* __restrict__ bias,
    const float* __restrict__ resid,
    void* __restrict__ Cout,
    int M, int N, int K)
{
  __shared__ float As[16][68];   // [k][m], pad 68 -> conflict-free float4 reads
  __shared__ float Bs[16][68];   // [k][n]
  const int tid = threadIdx.x;
  const int m0 = blockIdx.y * 64, n0 = blockIdx.x * 64;
  const int ty = tid >> 4, tx = tid & 15;
  const int ar = tid >> 2, ak0 = (tid & 3) * 4;   // A loader: 64 rows x 16 k
  const int bk = tid >> 4, bn0 = (tid & 15) * 4;  // B loader: 16 k x 64 n

  float acc[4][4] = {};

  for (int k0 = 0; k0 < K; k0 += 16) {
    {
      ushort4 av = *(const ushort4*)(A + (size_t)(m0 + ar) * K + k0 + ak0);
      As[ak0 + 0][ar] = bits2f(av.x);
      As[ak0 + 1][ar] = bits2f(av.y);
      As[ak0 + 2][ar] = bits2f(av.z);
      As[ak0 + 3][ar] = bits2f(av.w);
    }
    {
      float4 bv = *(const float4*)(B + (size_t)(k0 + bk) * N + n0 + bn0);
      Bs[bk][bn0 + 0] = bv.x;
      Bs[bk][bn0 + 1] = bv.y;
      Bs[bk][bn0 + 2] = bv.z;
      Bs[bk][bn0 + 3] = bv.w;
    }
    __syncthreads();
    #pragma unroll 8
    for (int kk = 0; kk < 16; ++kk) {
      float4 a4 = *(const float4*)&As[kk][ty * 4];
      float4 b4 = *(const float4*)&Bs[kk][tx * 4];
      const float a[4] = {a4.x, a4.y, a4.z, a4.w};
      const float b[4] = {b4.x, b4.y, b4.z, b4.w};
      #pragma unroll
      for (int i = 0; i < 4; ++i)
        #pragma unroll
        for (int j = 0; j < 4; ++j)
          acc[i][j] = fmaf(a[i], b[j], acc[i][j]);
    }
    __syncthreads();
  }

  #pragma unroll
  for (int i = 0; i < 4; ++i) {
    const int r = m0 + ty * 4 + i;
    const int c = n0 + tx * 4;
    const size_t idx = (size_t)r * N + c;
    float4 bia = *(const float4*)(bias + c);
    float v[4] = { acc[i][0] + bia.x, acc[i][1] + bia.y,
                   acc[i][2] + bia.z, acc[i][3] + bia.w };
    if constexpr (EPI == 0) {
      ushort4 o4 = { f2bits(v[0]), f2bits(v[1]), f2bits(v[2]), f2bits(v[3]) };
      *(ushort4*)((unsigned short*)Cout + idx) = o4;
    } else if constexpr (EPI == 1) {
      float4 r4 = *(const float4*)(resid + idx);
      float4 o4 = { v[0] + r4.x, v[1] + r4.y, v[2] + r4.z, v[3] + r4.w };
      *(float4*)((float*)Cout + idx) = o4;
    } else if constexpr (EPI == 2) {
      #pragma unroll
      for (int j = 0; j < 4; ++j)
        v[j] = 0.5f * v[j] * (1.0f + erff(v[j] * 0.70710678118654752f));
      ushort4 o4 = { f2bits(v[0]), f2bits(v[1]), f2bits(v[2]), f2bits(v[3]) };
      *(ushort4*)((unsigned short*)Cout + idx) = o4;
    } else {
      float4 r4 = *(const float4*)(resid + idx);
      float4 o4 = { v[0] + r4.x, v[1] + r4.y, v[2] + r4.z, v[3] + r4.w };
      *(float4*)((float*)Cout + idx) = o4;
    }
  }
}

// ---------------- Flash-style causal attention (bf16 qkv in, bf16 o out) ----------------
// qkv: [B*T, 3072] bf16 (q | k | v, each 1024 = 16 heads x 64)
// o:   [B*T, 1024] bf16. attn-weight scaling: softmax(qk) * 1024^-0.5 (1/32).
__global__ __launch_bounds__(256) void attn_k(const unsigned short* __restrict__ qkv,
                                              unsigned short* __restrict__ o)
{
  __shared__ unsigned short QsT[64][64]; // [dim][tok] bf16
  __shared__ unsigned short KsT[64][64]; // [dim][tok] bf16
  __shared__ unsigned short Vs[64][64];  // [tok][dim] bf16
  __shared__ float SsT[64][64];          // [kcol][qrow]
  __shared__ float m_s[64], l_s[64], al_s[64];

  const int tid = threadIdx.x;
  const int qt = blockIdx.x, bh = blockIdx.y;
  const int b = bh >> 4, h = bh & 15;
  const int q0 = qt * 64;
  const size_t base = (size_t)b * 2048 * 3072;
  const int qcol = h * 64, kcol = 1024 + h * 64, vcol = 2048 + h * 64;
  const int ty = tid >> 4, tx = tid & 15;
  const int lr = tid >> 2, lc0 = (tid & 3) * 16;

  { // stage Q transposed (once)
    const unsigned short* src = qkv + base + (size_t)(q0 + lr) * 3072 + qcol + lc0;
    union { uint4 u[2]; unsigned short s[16]; } d;
    d.u[0] = *(const uint4*)src;
    d.u[1] = *(const uint4*)(src + 8);
    #pragma unroll
    for (int i = 0; i < 16; ++i) QsT[lc0 + i][lr] = d.s[i];
  }
  if (tid < 64) { m_s[tid] = -3.0e38f; l_s[tid] = 0.0f; }
  float acc[4][4] = {};
  __syncthreads();

  for (int kt = 0; kt <= qt; ++kt) {
    const int k0 = kt * 64;
    { // stage K transposed, V natural
      const unsigned short* ksrc = qkv + base + (size_t)(k0 + lr) * 3072 + kcol + lc0;
      union { uint4 u[2]; unsigned short s[16]; } d;
      d.u[0] = *(const uint4*)ksrc;
      d.u[1] = *(const uint4*)(ksrc + 8);
      #pragma unroll
      for (int i = 0; i < 16; ++i) KsT[lc0 + i][lr] = d.s[i];
      const unsigned short* vsrc = qkv + base + (size_t)(k0 + lr) * 3072 + vcol + lc0;
      *(uint4*)&Vs[lr][lc0]     = *(const uint4*)vsrc;
      *(uint4*)&Vs[lr][lc0 + 8] = *(const uint4*)(vsrc + 8);
    }
    __syncthreads();

    { // S = Q K^T (4x4 per thread), masked, store transposed
      float s[4][4] = {};
      #pragma unroll 4
      for (int dd = 0; dd < 64; ++dd) {
        ushort4 qa = *(const ushort4*)&QsT[dd][ty * 4];
        ushort4 kb = *(const ushort4*)&KsT[dd][tx * 4];
        float qf[4] = {bits2f(qa.x), bits2f(qa.y), bits2f(qa.z), bits2f(qa.w)};
        float kf[4] = {bits2f(kb.x), bits2f(kb.y), bits2f(kb.z), bits2f(kb.w)};
        #pragma unroll
        for (int i = 0; i < 4; ++i)
          #pragma unroll
          for (int j = 0; j < 4; ++j)
            s[i][j] = fmaf(qf[i], kf[j], s[i][j]);
      }
      if (kt == qt) {
        #pragma unroll
        for (int i = 0; i < 4; ++i)
          #pragma unroll
          for (int j = 0; j < 4; ++j)
            if (k0 + tx * 4 + j > q0 + ty * 4 + i) s[i][j] = -3.0e38f;
      }
      #pragma unroll
      for (int j = 0; j < 4; ++j) {
        float4 col = { s[0][j], s[1][j], s[2][j], s[3][j] };
        *(float4*)&SsT[tx * 4 + j][ty * 4] = col;
      }
    }
    __syncthreads();

    if (tid < 64) { // online-softmax row pass (wave 0; SsT layout -> conflict-free)
      const float mold = m_s[tid];
      float mx = mold;
      #pragma unroll 8
      for (int j = 0; j < 64; ++j) mx = fmaxf(mx, SsT[j][tid]);
      const float alpha = __expf(mold - mx);
      float sum = 0.0f;
      #pragma unroll 8
      for (int j = 0; j < 64; ++j) {
        float p = __expf(SsT[j][tid] - mx);
        SsT[j][tid] = p;
        sum += p;
      }
      l_s[tid] = l_s[tid] * alpha + sum;
      m_s[tid] = mx;
      al_s[tid] = alpha;
    }
    __syncthreads();

    { // rescale + O += P V
      float al[4];
      #pragma unroll
      for (int i = 0; i < 4; ++i) al[i] = al_s[ty * 4 + i];
      #pragma unroll
      for (int i = 0; i < 4; ++i)
        #pragma unroll
        for (int j = 0; j < 4; ++j) acc[i][j] *= al[i];
      #pragma unroll 4
      for (int dd = 0; dd < 64; ++dd) {
        float4 p4 = *(const float4*)&SsT[dd][ty * 4];
        ushort4 vb = *(const ushort4*)&Vs[dd][tx * 4];
        float pf[4] = {p4.x, p4.y, p4.z, p4.w};
        float vf[4] = {bits2f(vb.x), bits2f(vb.y), bits2f(vb.z), bits2f(vb.w)};
        #pragma unroll
        for (int i = 0; i < 4; ++i)
          #pragma unroll
          for (int j = 0; j < 4; ++j)
            acc[i][j] = fmaf(pf[i], vf[j], acc[i][j]);
      }
    }
    __syncthreads();
  }

  #pragma unroll
  for (int i = 0; i < 4; ++i) {
    const int r = ty * 4 + i;
    const float inv = 0.03125f / l_s[r];
    const size_t orow = ((size_t)b * 2048 + q0 + r) * 1024 + h * 64 + tx * 4;
    ushort4 o4 = { f2bits(acc[i][0] * inv), f2bits(acc[i][1] * inv),
                   f2bits(acc[i][2] * inv), f2bits(acc[i][3] * inv) };
    *(ushort4*)(o + orow) = o4;
  }
}

extern "C" void kernel_launch(void* const* d_in, const int* in_sizes, int n_in,
                              void* d_out, int out_size, void* d_ws, size_t ws_size,
                              hipStream_t stream)
{
  (void)in_sizes; (void)n_in; (void)out_size; (void)ws_size;
  const float* x      = (const float*)d_in[0];
  const float* w_attn = (const float*)d_in[1];
  const float* b_attn = (const float*)d_in[2];
  const float* w_proj = (const float*)d_in[3];
  const float* b_proj = (const float*)d_in[4];
  const float* w_fc1  = (const float*)d_in[5];
  const float* b_fc1  = (const float*)d_in[6];
  const float* w_fc2  = (const float*)d_in[7];
  const float* b_fc2  = (const float*)d_in[8];
  const float* g1     = (const float*)d_in[9];
  const float* g2     = (const float*)d_in[10];
  float* out = (float*)d_out;

  // ws layout (80 MB): h/ov bf16 @0 (8MB), qkv/h2 bf16 @8MB (24MB),
  //                    x1 f32 @32MB (16MB), h3 bf16 @48MB (32MB)
  char* ws = (char*)d_ws;
  unsigned short* h   = (unsigned short*)(ws);
  unsigned short* qkv = (unsigned short*)(ws + ((size_t)8  << 20));
  unsigned short* ov  = (unsigned short*)(ws);                       // reuse h
  float*          x1  = (float*)         (ws + ((size_t)32 << 20));
  unsigned short* h2  = (unsigned short*)(ws + ((size_t)8  << 20));  // reuse qkv
  unsigned short* h3  = (unsigned short*)(ws + ((size_t)48 << 20));

  const int M = 4096;
  rmsnorm_k<<<M, 256, 0, stream>>>(x, g1, h);
  gemm_k<0><<<dim3(3072 / 64, M / 64), 256, 0, stream>>>(h,  w_attn, b_attn, nullptr, qkv, M, 3072, 1024);
  attn_k<<<dim3(32, 32), 256, 0, stream>>>(qkv, ov);
  gemm_k<1><<<dim3(1024 / 64, M / 64), 256, 0, stream>>>(ov, w_proj, b_proj, x,  x1,  M, 1024, 1024);
  rmsnorm_k<<<M, 256, 0, stream>>>(x1, g2, h2);
  gemm_k<2><<<dim3(4096 / 64, M / 64), 256, 0, stream>>>(h2, w_fc1,  b_fc1,  nullptr, h3, M, 4096, 1024);
  gemm_k<3><<<dim3(1024 / 64, M / 64), 256, 0, stream>>>(h3, w_fc2,  b_fc2,  x1, out, M, 1024, 4096);
}

// Round 3
// 1150.105 us; speedup vs baseline: 1.8967x; 1.8967x over previous
//
#include <hip/hip_runtime.h>
#include <hip/hip_bf16.h>

// Transformer block for MI355X. Round 3: MFMA GEMMs (m97-style: 128x128 tile,
// global_load_lds width=16, XOR-swizzled LDS, bf16 16x16x32 MFMA).
// Attention kept identical to round 2 for clean A/B.

typedef __hip_bfloat16 bf16;
typedef __attribute__((ext_vector_type(8))) short short8;   // 8 bf16 = 4 VGPRs
typedef __attribute__((ext_vector_type(4))) float floatx4;  // MFMA C/D frag

__device__ __forceinline__ float bits2f(unsigned short u) {
  union { unsigned int i; float f; } c; c.i = ((unsigned int)u) << 16; return c.f;
}
__device__ __forceinline__ unsigned short f2bits(float f) {
  bf16 b = __float2bfloat16(f);
  union { bf16 b; unsigned short u; } c; c.b = b; return c.u;
}

__device__ __forceinline__ void gld_lds16(const unsigned short* g, unsigned short* l) {
  __builtin_amdgcn_global_load_lds(
      (const __attribute__((address_space(1))) void*)g,
      (__attribute__((address_space(3))) void*)l, 16, 0, 0);
}

// ---------------- RMSNorm: f32 in, f32 gamma, bf16 out ----------------
__global__ __launch_bounds__(256) void rmsnorm_k(const float* __restrict__ x,
                                                 const float* __restrict__ g,
                                                 unsigned short* __restrict__ out)
{
  const int row = blockIdx.x, tid = threadIdx.x;
  const size_t rb = (size_t)row * 1024;
  float4 xv = *(const float4*)(x + rb + tid * 4);
  float v[4] = {xv.x, xv.y, xv.z, xv.w};
  float s = v[0]*v[0] + v[1]*v[1] + v[2]*v[2] + v[3]*v[3];
  #pragma unroll
  for (int off = 32; off > 0; off >>= 1) s += __shfl_down(s, off, 64);
  __shared__ float part[4];
  if ((tid & 63) == 0) part[tid >> 6] = s;
  __syncthreads();
  const float tot = part[0] + part[1] + part[2] + part[3];
  const float sc = rsqrtf(tot * (1.0f / 1024.0f) + 1.1920929e-07f);
  float4 gv = *(const float4*)(g + tid * 4);
  ushort4 o4 = { f2bits(v[0] * sc * gv.x), f2bits(v[1] * sc * gv.y),
                 f2bits(v[2] * sc * gv.z), f2bits(v[3] * sc * gv.w) };
  *(ushort4*)(out + rb + tid * 4) = o4;
}

// ---------------- Weight prep: W f32 [K,N] -> WT bf16 [N,K] ----------------
__global__ __launch_bounds__(256) void wprep_k(const float* __restrict__ in,
                                               unsigned short* __restrict__ out,
                                               int K, int N)
{
  __shared__ unsigned short tile[32][33];
  const int tid = threadIdx.x;
  const int k0 = blockIdx.y * 32, n0 = blockIdx.x * 32;
  const int tr = tid >> 3, tc4 = (tid & 7) * 4;
  float4 v = *(const float4*)(in + (size_t)(k0 + tr) * N + n0 + tc4);
  tile[tr][tc4 + 0] = f2bits(v.x);
  tile[tr][tc4 + 1] = f2bits(v.y);
  tile[tr][tc4 + 2] = f2bits(v.z);
  tile[tr][tc4 + 3] = f2bits(v.w);
  __syncthreads();
  ushort4 o = { tile[tc4 + 0][tr], tile[tc4 + 1][tr],
                tile[tc4 + 2][tr], tile[tc4 + 3][tr] };
  *(ushort4*)(out + (size_t)(n0 + tr) * K + k0 + tc4) = o;
}

// ---------------- MFMA GEMM: C = A[M,K](bf16) @ BT[N,K]^T(bf16) + bias(f32) ----------------
// 128x128 block tile, BK=32, 4 waves each owning a 64x64 quadrant (4x4 MFMA tiles).
// LDS slot swizzle: slot(row,kq) = row*4 + (kq ^ ((row>>1)&3)); 16B slots; the
// global_load_lds lane order IS slot order (lane-contiguous DMA constraint),
// and frag ds_read_b128 lands at 2-way bank aliasing (free).
// EPI 0: -> bf16 out | 1: +f32 resid -> f32 | 2: GELU -> bf16 | 3: +f32 resid -> f32
template<int EPI>
__global__ __launch_bounds__(256) void gemm_mfma_k(
    const unsigned short* __restrict__ A,
    const unsigned short* __restrict__ BT,
    const float* __restrict__ bias,
    const float* __restrict__ resid,
    void* __restrict__ Cout,
    int M, int N, int K)
{
  __shared__ __align__(16) unsigned short As[128 * 32];
  __shared__ __align__(16) unsigned short Bs[128 * 32];
  const int tid = threadIdx.x;
  const int lane = tid & 63;
  const int wv = tid >> 6;
  const int m0 = blockIdx.y * 128, n0 = blockIdx.x * 128;
  const int wm = (wv >> 1) * 64, wn = (wv & 1) * 64;

  // staging: 512 slots per matrix, 2 per thread (s0 = tid, s1 = tid+256)
  const int s0 = tid, s1 = tid + 256;
  const int r0 = s0 >> 2, kq0 = (s0 & 3) ^ ((r0 >> 1) & 3);
  const int r1 = s1 >> 2, kq1 = (s1 & 3) ^ ((r1 >> 1) & 3);
  const unsigned short* Ab = A  + (size_t)m0 * K;
  const unsigned short* Bb = BT + (size_t)n0 * K;
  const size_t ga0 = (size_t)r0 * K + kq0 * 8;
  const size_t ga1 = (size_t)r1 * K + kq1 * 8;

  floatx4 acc[4][4];
  #pragma unroll
  for (int i = 0; i < 4; ++i)
    #pragma unroll
    for (int j = 0; j < 4; ++j)
      acc[i][j] = (floatx4){0.f, 0.f, 0.f, 0.f};

  // precompute frag slot offsets (in shorts)
  int aoff[4], boff[4];
  #pragma unroll
  for (int i = 0; i < 4; ++i) {
    int ra = wm + i * 16 + (lane & 15);
    aoff[i] = (ra * 4 + ((lane >> 4) ^ ((ra >> 1) & 3))) * 8;
    int rb = wn + i * 16 + (lane & 15);
    boff[i] = (rb * 4 + ((lane >> 4) ^ ((rb >> 1) & 3))) * 8;
  }

  for (int k0 = 0; k0 < K; k0 += 32) {
    __syncthreads();
    gld_lds16(Ab + ga0 + k0, As + s0 * 8);
    gld_lds16(Ab + ga1 + k0, As + s1 * 8);
    gld_lds16(Bb + ga0 + k0, Bs + s0 * 8);
    gld_lds16(Bb + ga1 + k0, Bs + s1 * 8);
    __syncthreads();

    short8 af[4], bfr[4];
    #pragma unroll
    for (int i = 0; i < 4; ++i) {
      af[i]  = *(const short8*)(As + aoff[i]);
      bfr[i] = *(const short8*)(Bs + boff[i]);
    }
    #pragma unroll
    for (int i = 0; i < 4; ++i)
      #pragma unroll
      for (int j = 0; j < 4; ++j)
        acc[i][j] = __builtin_amdgcn_mfma_f32_16x16x32_bf16(af[i], bfr[j], acc[i][j], 0, 0, 0);
  }

  // epilogue: C[m = (lane>>4)*4 + r][n = lane&15] per 16x16 tile (m89-verified)
  #pragma unroll
  for (int i = 0; i < 4; ++i) {
    #pragma unroll
    for (int j = 0; j < 4; ++j) {
      const int rbase = m0 + wm + i * 16 + (lane >> 4) * 4;
      const int c = n0 + wn + j * 16 + (lane & 15);
      const float bia = bias[c];
      #pragma unroll
      for (int r = 0; r < 4; ++r) {
        float v = acc[i][j][r] + bia;
        const size_t idx = (size_t)(rbase + r) * N + c;
        if constexpr (EPI == 0) {
          ((unsigned short*)Cout)[idx] = f2bits(v);
        } else if constexpr (EPI == 1) {
          ((float*)Cout)[idx] = v + resid[idx];
        } else if constexpr (EPI == 2) {
          v = 0.5f * v * (1.0f + erff(v * 0.70710678118654752f));
          ((unsigned short*)Cout)[idx] = f2bits(v);
        } else {
          ((float*)Cout)[idx] = v + resid[idx];
        }
      }
    }
  }
}

// ---------------- Flash-style causal attention (unchanged from round 2) ----------------
__global__ __launch_bounds__(256) void attn_k(const unsigned short* __restrict__ qkv,
                                              unsigned short* __restrict__ o)
{
  __shared__ unsigned short QsT[64][64]; // [dim][tok] bf16
  __shared__ unsigned short KsT[64][64]; // [dim][tok] bf16
  __shared__ unsigned short Vs[64][64];  // [tok][dim] bf16
  __shared__ float SsT[64][64];          // [kcol][qrow]
  __shared__ float m_s[64], l_s[64], al_s[64];

  const int tid = threadIdx.x;
  const int qt = blockIdx.x, bh = blockIdx.y;
  const int b = bh >> 4, h = bh & 15;
  const int q0 = qt * 64;
  const size_t base = (size_t)b * 2048 * 3072;
  const int qcol = h * 64, kcol = 1024 + h * 64, vcol = 2048 + h * 64;
  const int ty = tid >> 4, tx = tid & 15;
  const int lr = tid >> 2, lc0 = (tid & 3) * 16;

  { // stage Q transposed (once)
    const unsigned short* src = qkv + base + (size_t)(q0 + lr) * 3072 + qcol + lc0;
    union { uint4 u[2]; unsigned short s[16]; } d;
    d.u[0] = *(const uint4*)src;
    d.u[1] = *(const uint4*)(src + 8);
    #pragma unroll
    for (int i = 0; i < 16; ++i) QsT[lc0 + i][lr] = d.s[i];
  }
  if (tid < 64) { m_s[tid] = -3.0e38f; l_s[tid] = 0.0f; }
  float acc[4][4] = {};
  __syncthreads();

  for (int kt = 0; kt <= qt; ++kt) {
    const int k0 = kt * 64;
    { // stage K transposed, V natural
      const unsigned short* ksrc = qkv + base + (size_t)(k0 + lr) * 3072 + kcol + lc0;
      union { uint4 u[2]; unsigned short s[16]; } d;
      d.u[0] = *(const uint4*)ksrc;
      d.u[1] = *(const uint4*)(ksrc + 8);
      #pragma unroll
      for (int i = 0; i < 16; ++i) KsT[lc0 + i][lr] = d.s[i];
      const unsigned short* vsrc = qkv + base + (size_t)(k0 + lr) * 3072 + vcol + lc0;
      *(uint4*)&Vs[lr][lc0]     = *(const uint4*)vsrc;
      *(uint4*)&Vs[lr][lc0 + 8] = *(const uint4*)(vsrc + 8);
    }
    __syncthreads();

    { // S = Q K^T (4x4 per thread), masked, store transposed
      float s[4][4] = {};
      #pragma unroll 4
      for (int dd = 0; dd < 64; ++dd) {
        ushort4 qa = *(const ushort4*)&QsT[dd][ty * 4];
        ushort4 kb = *(const ushort4*)&KsT[dd][tx * 4];
        float qf[4] = {bits2f(qa.x), bits2f(qa.y), bits2f(qa.z), bits2f(qa.w)};
        float kf[4] = {bits2f(kb.x), bits2f(kb.y), bits2f(kb.z), bits2f(kb.w)};
        #pragma unroll
        for (int i = 0; i < 4; ++i)
          #pragma unroll
          for (int j = 0; j < 4; ++j)
            s[i][j] = fmaf(qf[i], kf[j], s[i][j]);
      }
      if (kt == qt) {
        #pragma unroll
        for (int i = 0; i < 4; ++i)
          #pragma unroll
          for (int j = 0; j < 4; ++j)
            if (k0 + tx * 4 + j > q0 + ty * 4 + i) s[i][j] = -3.0e38f;
      }
      #pragma unroll
      for (int j = 0; j < 4; ++j) {
        float4 col = { s[0][j], s[1][j], s[2][j], s[3][j] };
        *(float4*)&SsT[tx * 4 + j][ty * 4] = col;
      }
    }
    __syncthreads();

    if (tid < 64) { // online-softmax row pass
      const float mold = m_s[tid];
      float mx = mold;
      #pragma unroll 8
      for (int j = 0; j < 64; ++j) mx = fmaxf(mx, SsT[j][tid]);
      const float alpha = __expf(mold - mx);
      float sum = 0.0f;
      #pragma unroll 8
      for (int j = 0; j < 64; ++j) {
        float p = __expf(SsT[j][tid] - mx);
        SsT[j][tid] = p;
        sum += p;
      }
      l_s[tid] = l_s[tid] * alpha + sum;
      m_s[tid] = mx;
      al_s[tid] = alpha;
    }
    __syncthreads();

    { // rescale + O += P V
      float al[4];
      #pragma unroll
      for (int i = 0; i < 4; ++i) al[i] = al_s[ty * 4 + i];
      #pragma unroll
      for (int i = 0; i < 4; ++i)
        #pragma unroll
        for (int j = 0; j < 4; ++j) acc[i][j] *= al[i];
      #pragma unroll 4
      for (int dd = 0; dd < 64; ++dd) {
        float4 p4 = *(const float4*)&SsT[dd][ty * 4];
        ushort4 vb = *(const ushort4*)&Vs[dd][tx * 4];
        float pf[4] = {p4.x, p4.y, p4.z, p4.w};
        float vf[4] = {bits2f(vb.x), bits2f(vb.y), bits2f(vb.z), bits2f(vb.w)};
        #pragma unroll
        for (int i = 0; i < 4; ++i)
          #pragma unroll
          for (int j = 0; j < 4; ++j)
            acc[i][j] = fmaf(pf[i], vf[j], acc[i][j]);
      }
    }
    __syncthreads();
  }

  #pragma unroll
  for (int i = 0; i < 4; ++i) {
    const int r = ty * 4 + i;
    const float inv = 0.03125f / l_s[r];
    const size_t orow = ((size_t)b * 2048 + q0 + r) * 1024 + h * 64 + tx * 4;
    ushort4 o4 = { f2bits(acc[i][0] * inv), f2bits(acc[i][1] * inv),
                   f2bits(acc[i][2] * inv), f2bits(acc[i][3] * inv) };
    *(ushort4*)(o + orow) = o4;
  }
}

extern "C" void kernel_launch(void* const* d_in, const int* in_sizes, int n_in,
                              void* d_out, int out_size, void* d_ws, size_t ws_size,
                              hipStream_t stream)
{
  (void)in_sizes; (void)n_in; (void)out_size; (void)ws_size;
  const float* x      = (const float*)d_in[0];
  const float* w_attn = (const float*)d_in[1];
  const float* b_attn = (const float*)d_in[2];
  const float* w_proj = (const float*)d_in[3];
  const float* b_proj = (const float*)d_in[4];
  const float* w_fc1  = (const float*)d_in[5];
  const float* b_fc1  = (const float*)d_in[6];
  const float* w_fc2  = (const float*)d_in[7];
  const float* b_fc2  = (const float*)d_in[8];
  const float* g1     = (const float*)d_in[9];
  const float* g2     = (const float*)d_in[10];
  float* out = (float*)d_out;

  // ws layout (88 MB): h/ov bf16 @0 (8MB), qkv bf16 @8MB (24MB, h2 reuses 8..16MB),
  //                    x1 f32 @32MB (16MB), h3 bf16 @48MB (32MB), WT scratch @80MB (8MB)
  char* ws = (char*)d_ws;
  unsigned short* h   = (unsigned short*)(ws);
  unsigned short* qkv = (unsigned short*)(ws + ((size_t)8  << 20));
  unsigned short* ov  = (unsigned short*)(ws);                       // reuse h
  float*          x1  = (float*)         (ws + ((size_t)32 << 20));
  unsigned short* h2  = (unsigned short*)(ws + ((size_t)8  << 20));  // reuse qkv
  unsigned short* h3  = (unsigned short*)(ws + ((size_t)48 << 20));
  unsigned short* WT  = (unsigned short*)(ws + ((size_t)80 << 20));

  const int M = 4096;

  rmsnorm_k<<<M, 256, 0, stream>>>(x, g1, h);
  // qkv = h @ w_attn + b_attn
  wprep_k<<<dim3(3072 / 32, 1024 / 32), 256, 0, stream>>>(w_attn, WT, 1024, 3072);
  gemm_mfma_k<0><<<dim3(3072 / 128, M / 128), 256, 0, stream>>>(h, WT, b_attn, nullptr, qkv, M, 3072, 1024);
  attn_k<<<dim3(32, 32), 256, 0, stream>>>(qkv, ov);
  // x1 = x + ov @ w_proj + b_proj
  wprep_k<<<dim3(1024 / 32, 1024 / 32), 256, 0, stream>>>(w_proj, WT, 1024, 1024);
  gemm_mfma_k<1><<<dim3(1024 / 128, M / 128), 256, 0, stream>>>(ov, WT, b_proj, x, x1, M, 1024, 1024);
  rmsnorm_k<<<M, 256, 0, stream>>>(x1, g2, h2);
  // h3 = gelu(h2 @ w_fc1 + b_fc1)
  wprep_k<<<dim3(4096 / 32, 1024 / 32), 256, 0, stream>>>(w_fc1, WT, 1024, 4096);
  gemm_mfma_k<2><<<dim3(4096 / 128, M / 128), 256, 0, stream>>>(h2, WT, b_fc1, nullptr, h3, M, 4096, 1024);
  // out = x1 + h3 @ w_fc2 + b_fc2
  wprep_k<<<dim3(1024 / 32, 4096 / 32), 256, 0, stream>>>(w_fc2, WT, 4096, 1024);
  gemm_mfma_k<3><<<dim3(1024 / 128, M / 128), 256, 0, stream>>>(h3, WT, b_fc2, x1, out, M, 1024, 4096);
}

// Round 4
// 477.541 us; speedup vs baseline: 4.5680x; 2.4084x over previous
//
#include <hip/hip_runtime.h>
#include <hip/hip_bf16.h>

// Transformer block for MI355X. Round 4: MFMA flash attention (register softmax,
// O^T = V^T P^T trick for contiguous LDS frag reads). GEMMs unchanged from round 3.

typedef __hip_bfloat16 bf16;
typedef __attribute__((ext_vector_type(8))) short short8;   // 8 bf16 = 4 VGPRs
typedef __attribute__((ext_vector_type(4))) float floatx4;  // MFMA C/D frag

__device__ __forceinline__ float bits2f(unsigned short u) {
  union { unsigned int i; float f; } c; c.i = ((unsigned int)u) << 16; return c.f;
}
__device__ __forceinline__ unsigned short f2bits(float f) {
  bf16 b = __float2bfloat16(f);
  union { bf16 b; unsigned short u; } c; c.b = b; return c.u;
}

__device__ __forceinline__ void gld_lds16(const unsigned short* g, unsigned short* l) {
  __builtin_amdgcn_global_load_lds(
      (const __attribute__((address_space(1))) void*)g,
      (__attribute__((address_space(3))) void*)l, 16, 0, 0);
}

// ---------------- RMSNorm: f32 in, f32 gamma, bf16 out ----------------
__global__ __launch_bounds__(256) void rmsnorm_k(const float* __restrict__ x,
                                                 const float* __restrict__ g,
                                                 unsigned short* __restrict__ out)
{
  const int row = blockIdx.x, tid = threadIdx.x;
  const size_t rb = (size_t)row * 1024;
  float4 xv = *(const float4*)(x + rb + tid * 4);
  float v[4] = {xv.x, xv.y, xv.z, xv.w};
  float s = v[0]*v[0] + v[1]*v[1] + v[2]*v[2] + v[3]*v[3];
  #pragma unroll
  for (int off = 32; off > 0; off >>= 1) s += __shfl_down(s, off, 64);
  __shared__ float part[4];
  if ((tid & 63) == 0) part[tid >> 6] = s;
  __syncthreads();
  const float tot = part[0] + part[1] + part[2] + part[3];
  const float sc = rsqrtf(tot * (1.0f / 1024.0f) + 1.1920929e-07f);
  float4 gv = *(const float4*)(g + tid * 4);
  ushort4 o4 = { f2bits(v[0] * sc * gv.x), f2bits(v[1] * sc * gv.y),
                 f2bits(v[2] * sc * gv.z), f2bits(v[3] * sc * gv.w) };
  *(ushort4*)(out + rb + tid * 4) = o4;
}

// ---------------- Weight prep: W f32 [K,N] -> WT bf16 [N,K] ----------------
__global__ __launch_bounds__(256) void wprep_k(const float* __restrict__ in,
                                               unsigned short* __restrict__ out,
                                               int K, int N)
{
  __shared__ unsigned short tile[32][33];
  const int tid = threadIdx.x;
  const int k0 = blockIdx.y * 32, n0 = blockIdx.x * 32;
  const int tr = tid >> 3, tc4 = (tid & 7) * 4;
  float4 v = *(const float4*)(in + (size_t)(k0 + tr) * N + n0 + tc4);
  tile[tr][tc4 + 0] = f2bits(v.x);
  tile[tr][tc4 + 1] = f2bits(v.y);
  tile[tr][tc4 + 2] = f2bits(v.z);
  tile[tr][tc4 + 3] = f2bits(v.w);
  __syncthreads();
  ushort4 o = { tile[tc4 + 0][tr], tile[tc4 + 1][tr],
                tile[tc4 + 2][tr], tile[tc4 + 3][tr] };
  *(ushort4*)(out + (size_t)(n0 + tr) * K + k0 + tc4) = o;
}

// ---------------- MFMA GEMM (unchanged from round 3) ----------------
template<int EPI>
__global__ __launch_bounds__(256) void gemm_mfma_k(
    const unsigned short* __restrict__ A,
    const unsigned short* __restrict__ BT,
    const float* __restrict__ bias,
    const float* __restrict__ resid,
    void* __restrict__ Cout,
    int M, int N, int K)
{
  __shared__ __align__(16) unsigned short As[128 * 32];
  __shared__ __align__(16) unsigned short Bs[128 * 32];
  const int tid = threadIdx.x;
  const int lane = tid & 63;
  const int wv = tid >> 6;
  const int m0 = blockIdx.y * 128, n0 = blockIdx.x * 128;
  const int wm = (wv >> 1) * 64, wn = (wv & 1) * 64;

  const int s0 = tid, s1 = tid + 256;
  const int r0 = s0 >> 2, kq0 = (s0 & 3) ^ ((r0 >> 1) & 3);
  const int r1 = s1 >> 2, kq1 = (s1 & 3) ^ ((r1 >> 1) & 3);
  const unsigned short* Ab = A  + (size_t)m0 * K;
  const unsigned short* Bb = BT + (size_t)n0 * K;
  const size_t ga0 = (size_t)r0 * K + kq0 * 8;
  const size_t ga1 = (size_t)r1 * K + kq1 * 8;

  floatx4 acc[4][4];
  #pragma unroll
  for (int i = 0; i < 4; ++i)
    #pragma unroll
    for (int j = 0; j < 4; ++j)
      acc[i][j] = (floatx4){0.f, 0.f, 0.f, 0.f};

  int aoff[4], boff[4];
  #pragma unroll
  for (int i = 0; i < 4; ++i) {
    int ra = wm + i * 16 + (lane & 15);
    aoff[i] = (ra * 4 + ((lane >> 4) ^ ((ra >> 1) & 3))) * 8;
    int rb = wn + i * 16 + (lane & 15);
    boff[i] = (rb * 4 + ((lane >> 4) ^ ((rb >> 1) & 3))) * 8;
  }

  for (int k0 = 0; k0 < K; k0 += 32) {
    __syncthreads();
    gld_lds16(Ab + ga0 + k0, As + s0 * 8);
    gld_lds16(Ab + ga1 + k0, As + s1 * 8);
    gld_lds16(Bb + ga0 + k0, Bs + s0 * 8);
    gld_lds16(Bb + ga1 + k0, Bs + s1 * 8);
    __syncthreads();

    short8 af[4], bfr[4];
    #pragma unroll
    for (int i = 0; i < 4; ++i) {
      af[i]  = *(const short8*)(As + aoff[i]);
      bfr[i] = *(const short8*)(Bs + boff[i]);
    }
    #pragma unroll
    for (int i = 0; i < 4; ++i)
      #pragma unroll
      for (int j = 0; j < 4; ++j)
        acc[i][j] = __builtin_amdgcn_mfma_f32_16x16x32_bf16(af[i], bfr[j], acc[i][j], 0, 0, 0);
  }

  #pragma unroll
  for (int i = 0; i < 4; ++i) {
    #pragma unroll
    for (int j = 0; j < 4; ++j) {
      const int rbase = m0 + wm + i * 16 + (lane >> 4) * 4;
      const int c = n0 + wn + j * 16 + (lane & 15);
      const float bia = bias[c];
      #pragma unroll
      for (int r = 0; r < 4; ++r) {
        float v = acc[i][j][r] + bia;
        const size_t idx = (size_t)(rbase + r) * N + c;
        if constexpr (EPI == 0) {
          ((unsigned short*)Cout)[idx] = f2bits(v);
        } else if constexpr (EPI == 1) {
          ((float*)Cout)[idx] = v + resid[idx];
        } else if constexpr (EPI == 2) {
          v = 0.5f * v * (1.0f + erff(v * 0.70710678118654752f));
          ((unsigned short*)Cout)[idx] = f2bits(v);
        } else {
          ((float*)Cout)[idx] = v + resid[idx];
        }
      }
    }
  }
}

// ---------------- MFMA flash attention ----------------
// qkv: [B*T, 3072] bf16 (q|k|v, each 16 heads x 64). o: [B*T,1024] bf16.
// Block: 4 waves, Q-tile=128 (wave owns 32 q-rows), K-tile=64.
// S = Q K^T via 16x16x32 MFMA (A=Q, B=K, both [tok][dim] swizzle-staged).
// Softmax in registers (shfl_xor over lane bits 0-3 = row group).
// PV as O^T = V^T P^T: A-frag from VT[d][tok] (stride 72), B-frag from
// Ps[q][tok] (stride 72) -- all contiguous 16B LDS reads.
__global__ __launch_bounds__(256) void attn_mfma_k(const unsigned short* __restrict__ qkv,
                                                   unsigned short* __restrict__ o)
{
  __shared__ __align__(16) unsigned short Qs[128 * 64];  // swizzled chunks
  __shared__ __align__(16) unsigned short Ks[64 * 64];   // swizzled chunks
  __shared__ __align__(16) unsigned short VT[64 * 72];   // [d][tok], pad 72
  __shared__ __align__(16) unsigned short Ps[128 * 72];  // [q][tok], pad 72 (wave-own rows)
  __shared__ __align__(16) float stat_s[128];            // alpha / l (wave-own rows)

  const int tid = threadIdx.x, lane = tid & 63, wv = tid >> 6;
  const int quad = lane >> 4, l15 = lane & 15;
  const int qt = blockIdx.x, bh = blockIdx.y;
  const int b = bh >> 4, h = bh & 15;
  const int q0 = qt * 128;
  const size_t base = (size_t)b * 2048 * 3072;
  const int qcol = h * 64, kcol = 1024 + h * 64, vcol = 2048 + h * 64;

  // ---- stage Q once (1024 slots of 16B, chunk-XOR swizzle: cp = c ^ (row&7)) ----
  #pragma unroll
  for (int p = 0; p < 4; ++p) {
    int s = tid + 256 * p;
    int r = s >> 3, cp = s & 7, c = cp ^ (r & 7);
    gld_lds16(qkv + base + (size_t)(q0 + r) * 3072 + qcol + c * 8, Qs + s * 8);
  }
  __syncthreads();

  // ---- preload Q A-frags (row = wave q-row, k = dim) ----
  short8 qa[2][2];
  #pragma unroll
  for (int i = 0; i < 2; ++i)
    #pragma unroll
    for (int ks = 0; ks < 2; ++ks) {
      int ra = wv * 32 + i * 16 + l15;
      int cp = (ks * 4 + quad) ^ (ra & 7);
      qa[i][ks] = *(const short8*)(Qs + (ra * 8 + cp) * 8);
    }

  floatx4 oacc[4][2];  // O^T accumulator: [d-tile][q-subtile]
  #pragma unroll
  for (int dt = 0; dt < 4; ++dt)
    #pragma unroll
    for (int q2 = 0; q2 < 2; ++q2)
      oacc[dt][q2] = (floatx4){0.f, 0.f, 0.f, 0.f};
  float m_i[2][4], l_i[2][4];
  #pragma unroll
  for (int i = 0; i < 2; ++i)
    #pragma unroll
    for (int r = 0; r < 4; ++r) { m_i[i][r] = -3.0e38f; l_i[i][r] = 0.0f; }

  const int nkt = 2 * qt + 2;
  for (int kt = 0; kt < nkt; ++kt) {
    const int k0 = kt * 64;
    __syncthreads();  // prev-iter readers of Ks/VT done

    { // stage K (512 slots, swizzled DMA)
      int s = tid, r = s >> 3, cp = s & 7, c = cp ^ (r & 7);
      gld_lds16(qkv + base + (size_t)(k0 + r) * 3072 + kcol + c * 8, Ks + s * 8);
      s = tid + 256; r = s >> 3; cp = s & 7; c = cp ^ (r & 7);
      gld_lds16(qkv + base + (size_t)(k0 + r) * 3072 + kcol + c * 8, Ks + s * 8);
    }
    { // stage V transposed: thread owns tok pair (2p,2p+1) x 8 dims; packed b32 writes
      int p = tid & 31, dc = tid >> 5;
      const unsigned short* v0 = qkv + base + (size_t)(k0 + 2 * p) * 3072 + vcol + dc * 8;
      uint4 u0 = *(const uint4*)v0;
      uint4 u1 = *(const uint4*)(v0 + 3072);
      unsigned short* dst = VT + (size_t)(dc * 8) * 72 + 2 * p;
      *(unsigned int*)(dst + 0 * 72) = (u0.x & 0xffffu) | (u1.x << 16);
      *(unsigned int*)(dst + 1 * 72) = (u0.x >> 16)     | (u1.x & 0xffff0000u);
      *(unsigned int*)(dst + 2 * 72) = (u0.y & 0xffffu) | (u1.y << 16);
      *(unsigned int*)(dst + 3 * 72) = (u0.y >> 16)     | (u1.y & 0xffff0000u);
      *(unsigned int*)(dst + 4 * 72) = (u0.z & 0xffffu) | (u1.z << 16);
      *(unsigned int*)(dst + 5 * 72) = (u0.z >> 16)     | (u1.z & 0xffff0000u);
      *(unsigned int*)(dst + 6 * 72) = (u0.w & 0xffffu) | (u1.w << 16);
      *(unsigned int*)(dst + 7 * 72) = (u0.w >> 16)     | (u1.w & 0xffff0000u);
    }
    __syncthreads();  // staging visible (drains DMA vmcnt too)

    // ---- S = Q K^T ----
    short8 kb[4][2];
    #pragma unroll
    for (int j = 0; j < 4; ++j)
      #pragma unroll
      for (int ks = 0; ks < 2; ++ks) {
        int rb = j * 16 + l15;
        int cp = (ks * 4 + quad) ^ (rb & 7);
        kb[j][ks] = *(const short8*)(Ks + (rb * 8 + cp) * 8);
      }
    floatx4 s_[2][4];
    #pragma unroll
    for (int i = 0; i < 2; ++i)
      #pragma unroll
      for (int j = 0; j < 4; ++j)
        s_[i][j] = (floatx4){0.f, 0.f, 0.f, 0.f};
    #pragma unroll
    for (int i = 0; i < 2; ++i)
      #pragma unroll
      for (int j = 0; j < 4; ++j)
        #pragma unroll
        for (int ks = 0; ks < 2; ++ks)
          s_[i][j] = __builtin_amdgcn_mfma_f32_16x16x32_bf16(qa[i][ks], kb[j][ks], s_[i][j], 0, 0, 0);

    // ---- mask + online softmax (registers) + P write ----
    #pragma unroll
    for (int i = 0; i < 2; ++i) {
      const int rowmin = q0 + wv * 32 + i * 16;
      const int rowb = rowmin + quad * 4;
      if (k0 + 63 > rowmin) {  // diagonal tile: causal mask
        #pragma unroll
        for (int j = 0; j < 4; ++j) {
          const int col = k0 + j * 16 + l15;
          #pragma unroll
          for (int r = 0; r < 4; ++r)
            if (col > rowb + r) s_[i][j][r] = -3.0e38f;
        }
      }
      float fm[4], al[4], rs[4];
      #pragma unroll
      for (int r = 0; r < 4; ++r)
        fm[r] = fmaxf(fmaxf(s_[i][0][r], s_[i][1][r]), fmaxf(s_[i][2][r], s_[i][3][r]));
      #pragma unroll
      for (int msk = 1; msk < 16; msk <<= 1)
        #pragma unroll
        for (int r = 0; r < 4; ++r)
          fm[r] = fmaxf(fm[r], __shfl_xor(fm[r], msk, 64));
      #pragma unroll
      for (int r = 0; r < 4; ++r) {
        const float mn = fmaxf(m_i[i][r], fm[r]);
        al[r] = __expf(m_i[i][r] - mn);
        m_i[i][r] = mn;
      }
      #pragma unroll
      for (int j = 0; j < 4; ++j)
        #pragma unroll
        for (int r = 0; r < 4; ++r)
          s_[i][j][r] = __expf(s_[i][j][r] - m_i[i][r]);
      #pragma unroll
      for (int r = 0; r < 4; ++r)
        rs[r] = (s_[i][0][r] + s_[i][1][r]) + (s_[i][2][r] + s_[i][3][r]);
      #pragma unroll
      for (int msk = 1; msk < 16; msk <<= 1)
        #pragma unroll
        for (int r = 0; r < 4; ++r)
          rs[r] += __shfl_xor(rs[r], msk, 64);
      #pragma unroll
      for (int r = 0; r < 4; ++r)
        l_i[i][r] = l_i[i][r] * al[r] + rs[r];
      if (l15 == 0) {  // publish alpha (wave-own rows; same-wave read below)
        float4 a4 = { al[0], al[1], al[2], al[3] };
        *(float4*)(stat_s + wv * 32 + i * 16 + quad * 4) = a4;
      }
      #pragma unroll
      for (int j = 0; j < 4; ++j)
        #pragma unroll
        for (int r = 0; r < 4; ++r)
          Ps[(size_t)(wv * 32 + i * 16 + quad * 4 + r) * 72 + j * 16 + l15] = f2bits(s_[i][j][r]);
    }

    // ---- O^T += V^T P^T (all wave-local LDS; no extra barrier) ----
    float alq[2];
    #pragma unroll
    for (int q2 = 0; q2 < 2; ++q2)
      alq[q2] = stat_s[wv * 32 + q2 * 16 + l15];
    #pragma unroll
    for (int dt = 0; dt < 4; ++dt)
      #pragma unroll
      for (int q2 = 0; q2 < 2; ++q2)
        #pragma unroll
        for (int r = 0; r < 4; ++r)
          oacc[dt][q2][r] *= alq[q2];

    short8 va[4][2], pb[2][2];
    #pragma unroll
    for (int dt = 0; dt < 4; ++dt)
      #pragma unroll
      for (int ks = 0; ks < 2; ++ks)
        va[dt][ks] = *(const short8*)(VT + (size_t)(dt * 16 + l15) * 72 + ks * 32 + quad * 8);
    #pragma unroll
    for (int q2 = 0; q2 < 2; ++q2)
      #pragma unroll
      for (int ks = 0; ks < 2; ++ks)
        pb[q2][ks] = *(const short8*)(Ps + (size_t)(wv * 32 + q2 * 16 + l15) * 72 + ks * 32 + quad * 8);
    #pragma unroll
    for (int dt = 0; dt < 4; ++dt)
      #pragma unroll
      for (int q2 = 0; q2 < 2; ++q2)
        #pragma unroll
        for (int ks = 0; ks < 2; ++ks)
          oacc[dt][q2] = __builtin_amdgcn_mfma_f32_16x16x32_bf16(va[dt][ks], pb[q2][ks], oacc[dt][q2], 0, 0, 0);
  }

  // ---- epilogue: O = O^T / l * 32^-1 ----
  if (l15 == 0) {
    #pragma unroll
    for (int i = 0; i < 2; ++i) {
      float4 l4 = { l_i[i][0], l_i[i][1], l_i[i][2], l_i[i][3] };
      *(float4*)(stat_s + wv * 32 + i * 16 + quad * 4) = l4;
    }
  }
  #pragma unroll
  for (int q2 = 0; q2 < 2; ++q2) {
    const float linv = 0.03125f / stat_s[wv * 32 + q2 * 16 + l15];
    const size_t row = (size_t)b * 2048 + q0 + wv * 32 + q2 * 16 + l15;
    #pragma unroll
    for (int dt = 0; dt < 4; ++dt) {
      const int col = h * 64 + dt * 16 + quad * 4;
      ushort4 o4 = { f2bits(oacc[dt][q2][0] * linv), f2bits(oacc[dt][q2][1] * linv),
                     f2bits(oacc[dt][q2][2] * linv), f2bits(oacc[dt][q2][3] * linv) };
      *(ushort4*)(o + row * 1024 + col) = o4;
    }
  }
}

extern "C" void kernel_launch(void* const* d_in, const int* in_sizes, int n_in,
                              void* d_out, int out_size, void* d_ws, size_t ws_size,
                              hipStream_t stream)
{
  (void)in_sizes; (void)n_in; (void)out_size; (void)ws_size;
  const float* x      = (const float*)d_in[0];
  const float* w_attn = (const float*)d_in[1];
  const float* b_attn = (const float*)d_in[2];
  const float* w_proj = (const float*)d_in[3];
  const float* b_proj = (const float*)d_in[4];
  const float* w_fc1  = (const float*)d_in[5];
  const float* b_fc1  = (const float*)d_in[6];
  const float* w_fc2  = (const float*)d_in[7];
  const float* b_fc2  = (const float*)d_in[8];
  const float* g1     = (const float*)d_in[9];
  const float* g2     = (const float*)d_in[10];
  float* out = (float*)d_out;

  // ws layout (88 MB): h/ov bf16 @0 (8MB), qkv bf16 @8MB (24MB, h2 reuses 8..16MB),
  //                    x1 f32 @32MB (16MB), h3 bf16 @48MB (32MB), WT scratch @80MB (8MB)
  char* ws = (char*)d_ws;
  unsigned short* h   = (unsigned short*)(ws);
  unsigned short* qkv = (unsigned short*)(ws + ((size_t)8  << 20));
  unsigned short* ov  = (unsigned short*)(ws);                       // reuse h
  float*          x1  = (float*)         (ws + ((size_t)32 << 20));
  unsigned short* h2  = (unsigned short*)(ws + ((size_t)8  << 20));  // reuse qkv
  unsigned short* h3  = (unsigned short*)(ws + ((size_t)48 << 20));
  unsigned short* WT  = (unsigned short*)(ws + ((size_t)80 << 20));

  const int M = 4096;

  rmsnorm_k<<<M, 256, 0, stream>>>(x, g1, h);
  wprep_k<<<dim3(3072 / 32, 1024 / 32), 256, 0, stream>>>(w_attn, WT, 1024, 3072);
  gemm_mfma_k<0><<<dim3(3072 / 128, M / 128), 256, 0, stream>>>(h, WT, b_attn, nullptr, qkv, M, 3072, 1024);
  attn_mfma_k<<<dim3(16, 32), 256, 0, stream>>>(qkv, ov);
  wprep_k<<<dim3(1024 / 32, 1024 / 32), 256, 0, stream>>>(w_proj, WT, 1024, 1024);
  gemm_mfma_k<1><<<dim3(1024 / 128, M / 128), 256, 0, stream>>>(ov, WT, b_proj, x, x1, M, 1024, 1024);
  rmsnorm_k<<<M, 256, 0, stream>>>(x1, g2, h2);
  wprep_k<<<dim3(4096 / 32, 1024 / 32), 256, 0, stream>>>(w_fc1, WT, 1024, 4096);
  gemm_mfma_k<2><<<dim3(4096 / 128, M / 128), 256, 0, stream>>>(h2, WT, b_fc1, nullptr, h3, M, 4096, 1024);
  wprep_k<<<dim3(1024 / 32, 4096 / 32), 256, 0, stream>>>(w_fc2, WT, 4096, 1024);
  gemm_mfma_k<3><<<dim3(1024 / 128, M / 128), 256, 0, stream>>>(h3, WT, b_fc2, x1, out, M, 1024, 4096);
}

// Round 7
// 477.193 us; speedup vs baseline: 4.5713x; 1.0007x over previous
//
#include <hip/hip_runtime.h>
#include <hip/hip_bf16.h>

// Transformer block for MI355X. Round 7: semantic revert to round 4 (last green).
// All kernel symbols renamed _r7 to force a fresh compile/load (rounds 5-6
// failed with bit-identical absmax across disjoint source changes -> suspect
// stale binary). Attention: 2D grid (qt=blockIdx.x, bh=blockIdx.y), exactly
// as the passing round-4 run.

typedef __hip_bfloat16 bf16;
typedef __attribute__((ext_vector_type(8))) short short8;   // 8 bf16 = 4 VGPRs
typedef __attribute__((ext_vector_type(4))) float floatx4;  // MFMA C/D frag

__device__ __forceinline__ float bits2f(unsigned short u) {
  union { unsigned int i; float f; } c; c.i = ((unsigned int)u) << 16; return c.f;
}
__device__ __forceinline__ unsigned short f2bits(float f) {
  bf16 b = __float2bfloat16(f);
  union { bf16 b; unsigned short u; } c; c.b = b; return c.u;
}

__device__ __forceinline__ void gld_lds16(const unsigned short* g, unsigned short* l) {
  __builtin_amdgcn_global_load_lds(
      (const __attribute__((address_space(1))) void*)g,
      (__attribute__((address_space(3))) void*)l, 16, 0, 0);
}

// ---------------- RMSNorm: f32 in, f32 gamma, bf16 out ----------------
__global__ __launch_bounds__(256) void rmsnorm_r7(const float* __restrict__ x,
                                                  const float* __restrict__ g,
                                                  unsigned short* __restrict__ out)
{
  const int row = blockIdx.x, tid = threadIdx.x;
  const size_t rb = (size_t)row * 1024;
  float4 xv = *(const float4*)(x + rb + tid * 4);
  float v[4] = {xv.x, xv.y, xv.z, xv.w};
  float s = v[0]*v[0] + v[1]*v[1] + v[2]*v[2] + v[3]*v[3];
  #pragma unroll
  for (int off = 32; off > 0; off >>= 1) s += __shfl_down(s, off, 64);
  __shared__ float part[4];
  if ((tid & 63) == 0) part[tid >> 6] = s;
  __syncthreads();
  const float tot = part[0] + part[1] + part[2] + part[3];
  const float sc = rsqrtf(tot * (1.0f / 1024.0f) + 1.1920929e-07f);
  float4 gv = *(const float4*)(g + tid * 4);
  ushort4 o4 = { f2bits(v[0] * sc * gv.x), f2bits(v[1] * sc * gv.y),
                 f2bits(v[2] * sc * gv.z), f2bits(v[3] * sc * gv.w) };
  *(ushort4*)(out + rb + tid * 4) = o4;
}

// ---------------- Weight prep: W f32 [K,N] -> WT bf16 [N,K] ----------------
__global__ __launch_bounds__(256) void wprep_r7(const float* __restrict__ in,
                                                unsigned short* __restrict__ out,
                                                int K, int N)
{
  __shared__ unsigned short tile[32][33];
  const int tid = threadIdx.x;
  const int k0 = blockIdx.y * 32, n0 = blockIdx.x * 32;
  const int tr = tid >> 3, tc4 = (tid & 7) * 4;
  float4 v = *(const float4*)(in + (size_t)(k0 + tr) * N + n0 + tc4);
  tile[tr][tc4 + 0] = f2bits(v.x);
  tile[tr][tc4 + 1] = f2bits(v.y);
  tile[tr][tc4 + 2] = f2bits(v.z);
  tile[tr][tc4 + 3] = f2bits(v.w);
  __syncthreads();
  ushort4 o = { tile[tc4 + 0][tr], tile[tc4 + 1][tr],
                tile[tc4 + 2][tr], tile[tc4 + 3][tr] };
  *(ushort4*)(out + (size_t)(n0 + tr) * K + k0 + tc4) = o;
}

// ---------------- MFMA GEMM: C = A[M,K](bf16) @ BT[N,K]^T(bf16) + bias(f32) ----------------
// 128x128 tile, BK=32, 4 waves each owning a 64x64 quadrant (4x4 MFMA tiles).
template<int EPI>
__global__ __launch_bounds__(256) void gemm_r7(
    const unsigned short* __restrict__ A,
    const unsigned short* __restrict__ BT,
    const float* __restrict__ bias,
    const float* __restrict__ resid,
    void* __restrict__ Cout,
    int M, int N, int K)
{
  __shared__ __align__(16) unsigned short As[128 * 32];
  __shared__ __align__(16) unsigned short Bs[128 * 32];
  const int tid = threadIdx.x;
  const int lane = tid & 63;
  const int wv = tid >> 6;
  const int m0 = blockIdx.y * 128, n0 = blockIdx.x * 128;
  const int wm = (wv >> 1) * 64, wn = (wv & 1) * 64;

  const int s0 = tid, s1 = tid + 256;
  const int r0 = s0 >> 2, kq0 = (s0 & 3) ^ ((r0 >> 1) & 3);
  const int r1 = s1 >> 2, kq1 = (s1 & 3) ^ ((r1 >> 1) & 3);
  const unsigned short* Ab = A  + (size_t)m0 * K;
  const unsigned short* Bb = BT + (size_t)n0 * K;
  const size_t ga0 = (size_t)r0 * K + kq0 * 8;
  const size_t ga1 = (size_t)r1 * K + kq1 * 8;

  floatx4 acc[4][4];
  #pragma unroll
  for (int i = 0; i < 4; ++i)
    #pragma unroll
    for (int j = 0; j < 4; ++j)
      acc[i][j] = (floatx4){0.f, 0.f, 0.f, 0.f};

  int aoff[4], boff[4];
  #pragma unroll
  for (int i = 0; i < 4; ++i) {
    int ra = wm + i * 16 + (lane & 15);
    aoff[i] = (ra * 4 + ((lane >> 4) ^ ((ra >> 1) & 3))) * 8;
    int rb = wn + i * 16 + (lane & 15);
    boff[i] = (rb * 4 + ((lane >> 4) ^ ((rb >> 1) & 3))) * 8;
  }

  for (int k0 = 0; k0 < K; k0 += 32) {
    __syncthreads();
    gld_lds16(Ab + ga0 + k0, As + s0 * 8);
    gld_lds16(Ab + ga1 + k0, As + s1 * 8);
    gld_lds16(Bb + ga0 + k0, Bs + s0 * 8);
    gld_lds16(Bb + ga1 + k0, Bs + s1 * 8);
    __syncthreads();

    short8 af[4], bfr[4];
    #pragma unroll
    for (int i = 0; i < 4; ++i) {
      af[i]  = *(const short8*)(As + aoff[i]);
      bfr[i] = *(const short8*)(Bs + boff[i]);
    }
    #pragma unroll
    for (int i = 0; i < 4; ++i)
      #pragma unroll
      for (int j = 0; j < 4; ++j)
        acc[i][j] = __builtin_amdgcn_mfma_f32_16x16x32_bf16(af[i], bfr[j], acc[i][j], 0, 0, 0);
  }

  #pragma unroll
  for (int i = 0; i < 4; ++i) {
    #pragma unroll
    for (int j = 0; j < 4; ++j) {
      const int rbase = m0 + wm + i * 16 + (lane >> 4) * 4;
      const int c = n0 + wn + j * 16 + (lane & 15);
      const float bia = bias[c];
      #pragma unroll
      for (int r = 0; r < 4; ++r) {
        float v = acc[i][j][r] + bia;
        const size_t idx = (size_t)(rbase + r) * N + c;
        if constexpr (EPI == 0) {
          ((unsigned short*)Cout)[idx] = f2bits(v);
        } else if constexpr (EPI == 1) {
          ((float*)Cout)[idx] = v + resid[idx];
        } else if constexpr (EPI == 2) {
          v = 0.5f * v * (1.0f + erff(v * 0.70710678118654752f));
          ((unsigned short*)Cout)[idx] = f2bits(v);
        } else {
          ((float*)Cout)[idx] = v + resid[idx];
        }
      }
    }
  }
}

// ---------------- MFMA flash attention (round-4 form: 2D grid) ----------------
// qkv: [B*T, 3072] bf16 (q|k|v, each 16 heads x 64). o: [B*T,1024] bf16.
// Block: 4 waves, Q-tile=128 (wave owns 32 q-rows), K-tile=64.
__global__ __launch_bounds__(256) void attn_r7(const unsigned short* __restrict__ qkv,
                                               unsigned short* __restrict__ o)
{
  __shared__ __align__(16) unsigned short Qs[128 * 64];  // swizzled chunks
  __shared__ __align__(16) unsigned short Ks[64 * 64];   // swizzled chunks
  __shared__ __align__(16) unsigned short VT[64 * 72];   // [d][tok], pad 72
  __shared__ __align__(16) unsigned short Ps[128 * 72];  // [q][tok], pad 72 (wave-own rows)
  __shared__ __align__(16) float stat_s[128];            // alpha / l (wave-own rows)

  const int tid = threadIdx.x, lane = tid & 63, wv = tid >> 6;
  const int quad = lane >> 4, l15 = lane & 15;
  const int qt = blockIdx.x, bh = blockIdx.y;
  const int b = bh >> 4, h = bh & 15;
  const int q0 = qt * 128;
  const size_t base = (size_t)b * 2048 * 3072;
  const int qcol = h * 64, kcol = 1024 + h * 64, vcol = 2048 + h * 64;

  // ---- stage Q once (1024 slots of 16B, chunk-XOR swizzle: cp = c ^ (row&7)) ----
  #pragma unroll
  for (int p = 0; p < 4; ++p) {
    int s = tid + 256 * p;
    int r = s >> 3, cp = s & 7, c = cp ^ (r & 7);
    gld_lds16(qkv + base + (size_t)(q0 + r) * 3072 + qcol + c * 8, Qs + s * 8);
  }
  __syncthreads();

  // ---- preload Q A-frags (row = wave q-row, k = dim) ----
  short8 qa[2][2];
  #pragma unroll
  for (int i = 0; i < 2; ++i)
    #pragma unroll
    for (int ks = 0; ks < 2; ++ks) {
      int ra = wv * 32 + i * 16 + l15;
      int cp = (ks * 4 + quad) ^ (ra & 7);
      qa[i][ks] = *(const short8*)(Qs + (ra * 8 + cp) * 8);
    }

  floatx4 oacc[4][2];  // O^T accumulator: [d-tile][q-subtile]
  #pragma unroll
  for (int dt = 0; dt < 4; ++dt)
    #pragma unroll
    for (int q2 = 0; q2 < 2; ++q2)
      oacc[dt][q2] = (floatx4){0.f, 0.f, 0.f, 0.f};
  float m_i[2][4], l_i[2][4];
  #pragma unroll
  for (int i = 0; i < 2; ++i)
    #pragma unroll
    for (int r = 0; r < 4; ++r) { m_i[i][r] = -3.0e38f; l_i[i][r] = 0.0f; }

  const int nkt = 2 * qt + 2;
  for (int kt = 0; kt < nkt; ++kt) {
    const int k0 = kt * 64;
    __syncthreads();  // prev-iter readers of Ks/VT done

    { // stage K (512 slots, swizzled DMA)
      int s = tid, r = s >> 3, cp = s & 7, c = cp ^ (r & 7);
      gld_lds16(qkv + base + (size_t)(k0 + r) * 3072 + kcol + c * 8, Ks + s * 8);
      s = tid + 256; r = s >> 3; cp = s & 7; c = cp ^ (r & 7);
      gld_lds16(qkv + base + (size_t)(k0 + r) * 3072 + kcol + c * 8, Ks + s * 8);
    }
    { // stage V transposed: thread owns tok pair (2p,2p+1) x 8 dims; packed b32 writes
      int p = tid & 31, dc = tid >> 5;
      const unsigned short* v0 = qkv + base + (size_t)(k0 + 2 * p) * 3072 + vcol + dc * 8;
      uint4 u0 = *(const uint4*)v0;
      uint4 u1 = *(const uint4*)(v0 + 3072);
      unsigned short* dst = VT + (size_t)(dc * 8) * 72 + 2 * p;
      *(unsigned int*)(dst + 0 * 72) = (u0.x & 0xffffu) | (u1.x << 16);
      *(unsigned int*)(dst + 1 * 72) = (u0.x >> 16)     | (u1.x & 0xffff0000u);
      *(unsigned int*)(dst + 2 * 72) = (u0.y & 0xffffu) | (u1.y << 16);
      *(unsigned int*)(dst + 3 * 72) = (u0.y >> 16)     | (u1.y & 0xffff0000u);
      *(unsigned int*)(dst + 4 * 72) = (u0.z & 0xffffu) | (u1.z << 16);
      *(unsigned int*)(dst + 5 * 72) = (u0.z >> 16)     | (u1.z & 0xffff0000u);
      *(unsigned int*)(dst + 6 * 72) = (u0.w & 0xffffu) | (u1.w << 16);
      *(unsigned int*)(dst + 7 * 72) = (u0.w >> 16)     | (u1.w & 0xffff0000u);
    }
    __syncthreads();  // staging visible (drains DMA vmcnt too)

    // ---- S = Q K^T ----
    short8 kb[4][2];
    #pragma unroll
    for (int j = 0; j < 4; ++j)
      #pragma unroll
      for (int ks = 0; ks < 2; ++ks) {
        int rb = j * 16 + l15;
        int cp = (ks * 4 + quad) ^ (rb & 7);
        kb[j][ks] = *(const short8*)(Ks + (rb * 8 + cp) * 8);
      }
    floatx4 s_[2][4];
    #pragma unroll
    for (int i = 0; i < 2; ++i)
      #pragma unroll
      for (int j = 0; j < 4; ++j)
        s_[i][j] = (floatx4){0.f, 0.f, 0.f, 0.f};
    #pragma unroll
    for (int i = 0; i < 2; ++i)
      #pragma unroll
      for (int j = 0; j < 4; ++j)
        #pragma unroll
        for (int ks = 0; ks < 2; ++ks)
          s_[i][j] = __builtin_amdgcn_mfma_f32_16x16x32_bf16(qa[i][ks], kb[j][ks], s_[i][j], 0, 0, 0);

    // ---- mask + online softmax (registers) + P write ----
    #pragma unroll
    for (int i = 0; i < 2; ++i) {
      const int rowmin = q0 + wv * 32 + i * 16;
      const int rowb = rowmin + quad * 4;
      if (k0 + 63 > rowmin) {  // diagonal tile: causal mask
        #pragma unroll
        for (int j = 0; j < 4; ++j) {
          const int col = k0 + j * 16 + l15;
          #pragma unroll
          for (int r = 0; r < 4; ++r)
            if (col > rowb + r) s_[i][j][r] = -3.0e38f;
        }
      }
      float fm[4], al[4], rs[4];
      #pragma unroll
      for (int r = 0; r < 4; ++r)
        fm[r] = fmaxf(fmaxf(s_[i][0][r], s_[i][1][r]), fmaxf(s_[i][2][r], s_[i][3][r]));
      #pragma unroll
      for (int msk = 1; msk < 16; msk <<= 1)
        #pragma unroll
        for (int r = 0; r < 4; ++r)
          fm[r] = fmaxf(fm[r], __shfl_xor(fm[r], msk, 64));
      #pragma unroll
      for (int r = 0; r < 4; ++r) {
        const float mn = fmaxf(m_i[i][r], fm[r]);
        al[r] = __expf(m_i[i][r] - mn);
        m_i[i][r] = mn;
      }
      #pragma unroll
      for (int j = 0; j < 4; ++j)
        #pragma unroll
        for (int r = 0; r < 4; ++r)
          s_[i][j][r] = __expf(s_[i][j][r] - m_i[i][r]);
      #pragma unroll
      for (int r = 0; r < 4; ++r)
        rs[r] = (s_[i][0][r] + s_[i][1][r]) + (s_[i][2][r] + s_[i][3][r]);
      #pragma unroll
      for (int msk = 1; msk < 16; msk <<= 1)
        #pragma unroll
        for (int r = 0; r < 4; ++r)
          rs[r] += __shfl_xor(rs[r], msk, 64);
      #pragma unroll
      for (int r = 0; r < 4; ++r)
        l_i[i][r] = l_i[i][r] * al[r] + rs[r];
      if (l15 == 0) {  // publish alpha (wave-own rows; same-wave read below)
        float4 a4 = { al[0], al[1], al[2], al[3] };
        *(float4*)(stat_s + wv * 32 + i * 16 + quad * 4) = a4;
      }
      #pragma unroll
      for (int j = 0; j < 4; ++j)
        #pragma unroll
        for (int r = 0; r < 4; ++r)
          Ps[(size_t)(wv * 32 + i * 16 + quad * 4 + r) * 72 + j * 16 + l15] = f2bits(s_[i][j][r]);
    }

    // ---- O^T += V^T P^T (all wave-local LDS; no extra barrier) ----
    float alq[2];
    #pragma unroll
    for (int q2 = 0; q2 < 2; ++q2)
      alq[q2] = stat_s[wv * 32 + q2 * 16 + l15];
    #pragma unroll
    for (int dt = 0; dt < 4; ++dt)
      #pragma unroll
      for (int q2 = 0; q2 < 2; ++q2)
        #pragma unroll
        for (int r = 0; r < 4; ++r)
          oacc[dt][q2][r] *= alq[q2];

    short8 va[4][2], pb[2][2];
    #pragma unroll
    for (int dt = 0; dt < 4; ++dt)
      #pragma unroll
      for (int ks = 0; ks < 2; ++ks)
        va[dt][ks] = *(const short8*)(VT + (size_t)(dt * 16 + l15) * 72 + ks * 32 + quad * 8);
    #pragma unroll
    for (int q2 = 0; q2 < 2; ++q2)
      #pragma unroll
      for (int ks = 0; ks < 2; ++ks)
        pb[q2][ks] = *(const short8*)(Ps + (size_t)(wv * 32 + q2 * 16 + l15) * 72 + ks * 32 + quad * 8);
    #pragma unroll
    for (int dt = 0; dt < 4; ++dt)
      #pragma unroll
      for (int q2 = 0; q2 < 2; ++q2)
        #pragma unroll
        for (int ks = 0; ks < 2; ++ks)
          oacc[dt][q2] = __builtin_amdgcn_mfma_f32_16x16x32_bf16(va[dt][ks], pb[q2][ks], oacc[dt][q2], 0, 0, 0);
  }

  // ---- epilogue: O = O^T / l * 32^-1 ----
  if (l15 == 0) {
    #pragma unroll
    for (int i = 0; i < 2; ++i) {
      float4 l4 = { l_i[i][0], l_i[i][1], l_i[i][2], l_i[i][3] };
      *(float4*)(stat_s + wv * 32 + i * 16 + quad * 4) = l4;
    }
  }
  #pragma unroll
  for (int q2 = 0; q2 < 2; ++q2) {
    const float linv = 0.03125f / stat_s[wv * 32 + q2 * 16 + l15];
    const size_t row = (size_t)b * 2048 + q0 + wv * 32 + q2 * 16 + l15;
    #pragma unroll
    for (int dt = 0; dt < 4; ++dt) {
      const int col = h * 64 + dt * 16 + quad * 4;
      ushort4 o4 = { f2bits(oacc[dt][q2][0] * linv), f2bits(oacc[dt][q2][1] * linv),
                     f2bits(oacc[dt][q2][2] * linv), f2bits(oacc[dt][q2][3] * linv) };
      *(ushort4*)(o + row * 1024 + col) = o4;
    }
  }
}

extern "C" void kernel_launch(void* const* d_in, const int* in_sizes, int n_in,
                              void* d_out, int out_size, void* d_ws, size_t ws_size,
                              hipStream_t stream)
{
  (void)in_sizes; (void)n_in; (void)out_size; (void)ws_size;
  const float* x      = (const float*)d_in[0];
  const float* w_attn = (const float*)d_in[1];
  const float* b_attn = (const float*)d_in[2];
  const float* w_proj = (const float*)d_in[3];
  const float* b_proj = (const float*)d_in[4];
  const float* w_fc1  = (const float*)d_in[5];
  const float* b_fc1  = (const float*)d_in[6];
  const float* w_fc2  = (const float*)d_in[7];
  const float* b_fc2  = (const float*)d_in[8];
  const float* g1     = (const float*)d_in[9];
  const float* g2     = (const float*)d_in[10];
  float* out = (float*)d_out;

  // ws layout (88 MB): h/ov bf16 @0 (8MB), qkv bf16 @8MB (24MB, h2 reuses 8..16MB),
  //                    x1 f32 @32MB (16MB), h3 bf16 @48MB (32MB), WT scratch @80MB (8MB)
  char* ws = (char*)d_ws;
  unsigned short* h   = (unsigned short*)(ws);
  unsigned short* qkv = (unsigned short*)(ws + ((size_t)8  << 20));
  unsigned short* ov  = (unsigned short*)(ws);                       // reuse h
  float*          x1  = (float*)         (ws + ((size_t)32 << 20));
  unsigned short* h2  = (unsigned short*)(ws + ((size_t)8  << 20));  // reuse qkv
  unsigned short* h3  = (unsigned short*)(ws + ((size_t)48 << 20));
  unsigned short* WT  = (unsigned short*)(ws + ((size_t)80 << 20));

  const int M = 4096;

  rmsnorm_r7<<<M, 256, 0, stream>>>(x, g1, h);
  wprep_r7<<<dim3(3072 / 32, 1024 / 32), 256, 0, stream>>>(w_attn, WT, 1024, 3072);
  gemm_r7<0><<<dim3(3072 / 128, M / 128), 256, 0, stream>>>(h, WT, b_attn, nullptr, qkv, M, 3072, 1024);
  attn_r7<<<dim3(16, 32), 256, 0, stream>>>(qkv, ov);
  wprep_r7<<<dim3(1024 / 32, 1024 / 32), 256, 0, stream>>>(w_proj, WT, 1024, 1024);
  gemm_r7<1><<<dim3(1024 / 128, M / 128), 256, 0, stream>>>(ov, WT, b_proj, x, x1, M, 1024, 1024);
  rmsnorm_r7<<<M, 256, 0, stream>>>(x1, g2, h2);
  wprep_r7<<<dim3(4096 / 32, 1024 / 32), 256, 0, stream>>>(w_fc1, WT, 1024, 4096);
  gemm_r7<2><<<dim3(4096 / 128, M / 128), 256, 0, stream>>>(h2, WT, b_fc1, nullptr, h3, M, 4096, 1024);
  wprep_r7<<<dim3(1024 / 32, 4096 / 32), 256, 0, stream>>>(w_fc2, WT, 4096, 1024);
  gemm_r7<3><<<dim3(1024 / 128, M / 128), 256, 0, stream>>>(h3, WT, b_fc2, x1, out, M, 1024, 4096);
}

// Round 8
// 451.864 us; speedup vs baseline: 4.8275x; 1.0561x over previous
//
#include <hip/hip_runtime.h>
#include <hip/hip_bf16.h>

// Transformer block for MI355X. Round 8: attention load balance via
// complementary Q-tile PAIR per block (qt0, 15-qt0 done sequentially in one
// block; every block = 34 k-iters, grid 8x32 = 256 uniform blocks).
// No blockIdx remapping (rounds 5/6 lesson). All symbols _r8 (fresh build).

typedef __hip_bfloat16 bf16;
typedef __attribute__((ext_vector_type(8))) short short8;   // 8 bf16 = 4 VGPRs
typedef __attribute__((ext_vector_type(4))) float floatx4;  // MFMA C/D frag

__device__ __forceinline__ float bits2f(unsigned short u) {
  union { unsigned int i; float f; } c; c.i = ((unsigned int)u) << 16; return c.f;
}
__device__ __forceinline__ unsigned short f2bits(float f) {
  bf16 b = __float2bfloat16(f);
  union { bf16 b; unsigned short u; } c; c.b = b; return c.u;
}

__device__ __forceinline__ void gld_lds16(const unsigned short* g, unsigned short* l) {
  __builtin_amdgcn_global_load_lds(
      (const __attribute__((address_space(1))) void*)g,
      (__attribute__((address_space(3))) void*)l, 16, 0, 0);
}

// ---------------- RMSNorm: f32 in, f32 gamma, bf16 out ----------------
__global__ __launch_bounds__(256) void rmsnorm_r8(const float* __restrict__ x,
                                                  const float* __restrict__ g,
                                                  unsigned short* __restrict__ out)
{
  const int row = blockIdx.x, tid = threadIdx.x;
  const size_t rb = (size_t)row * 1024;
  float4 xv = *(const float4*)(x + rb + tid * 4);
  float v[4] = {xv.x, xv.y, xv.z, xv.w};
  float s = v[0]*v[0] + v[1]*v[1] + v[2]*v[2] + v[3]*v[3];
  #pragma unroll
  for (int off = 32; off > 0; off >>= 1) s += __shfl_down(s, off, 64);
  __shared__ float part[4];
  if ((tid & 63) == 0) part[tid >> 6] = s;
  __syncthreads();
  const float tot = part[0] + part[1] + part[2] + part[3];
  const float sc = rsqrtf(tot * (1.0f / 1024.0f) + 1.1920929e-07f);
  float4 gv = *(const float4*)(g + tid * 4);
  ushort4 o4 = { f2bits(v[0] * sc * gv.x), f2bits(v[1] * sc * gv.y),
                 f2bits(v[2] * sc * gv.z), f2bits(v[3] * sc * gv.w) };
  *(ushort4*)(out + rb + tid * 4) = o4;
}

// ---------------- Weight prep: W f32 [K,N] -> WT bf16 [N,K] ----------------
__global__ __launch_bounds__(256) void wprep_r8(const float* __restrict__ in,
                                                unsigned short* __restrict__ out,
                                                int K, int N)
{
  __shared__ unsigned short tile[32][33];
  const int tid = threadIdx.x;
  const int k0 = blockIdx.y * 32, n0 = blockIdx.x * 32;
  const int tr = tid >> 3, tc4 = (tid & 7) * 4;
  float4 v = *(const float4*)(in + (size_t)(k0 + tr) * N + n0 + tc4);
  tile[tr][tc4 + 0] = f2bits(v.x);
  tile[tr][tc4 + 1] = f2bits(v.y);
  tile[tr][tc4 + 2] = f2bits(v.z);
  tile[tr][tc4 + 3] = f2bits(v.w);
  __syncthreads();
  ushort4 o = { tile[tc4 + 0][tr], tile[tc4 + 1][tr],
                tile[tc4 + 2][tr], tile[tc4 + 3][tr] };
  *(ushort4*)(out + (size_t)(n0 + tr) * K + k0 + tc4) = o;
}

// ---------------- MFMA GEMM: C = A[M,K](bf16) @ BT[N,K]^T(bf16) + bias(f32) ----------------
// 128x128 tile, BK=32, 4 waves each owning a 64x64 quadrant (4x4 MFMA tiles).
template<int EPI>
__global__ __launch_bounds__(256) void gemm_r8(
    const unsigned short* __restrict__ A,
    const unsigned short* __restrict__ BT,
    const float* __restrict__ bias,
    const float* __restrict__ resid,
    void* __restrict__ Cout,
    int M, int N, int K)
{
  __shared__ __align__(16) unsigned short As[128 * 32];
  __shared__ __align__(16) unsigned short Bs[128 * 32];
  const int tid = threadIdx.x;
  const int lane = tid & 63;
  const int wv = tid >> 6;
  const int m0 = blockIdx.y * 128, n0 = blockIdx.x * 128;
  const int wm = (wv >> 1) * 64, wn = (wv & 1) * 64;

  const int s0 = tid, s1 = tid + 256;
  const int r0 = s0 >> 2, kq0 = (s0 & 3) ^ ((r0 >> 1) & 3);
  const int r1 = s1 >> 2, kq1 = (s1 & 3) ^ ((r1 >> 1) & 3);
  const unsigned short* Ab = A  + (size_t)m0 * K;
  const unsigned short* Bb = BT + (size_t)n0 * K;
  const size_t ga0 = (size_t)r0 * K + kq0 * 8;
  const size_t ga1 = (size_t)r1 * K + kq1 * 8;

  floatx4 acc[4][4];
  #pragma unroll
  for (int i = 0; i < 4; ++i)
    #pragma unroll
    for (int j = 0; j < 4; ++j)
      acc[i][j] = (floatx4){0.f, 0.f, 0.f, 0.f};

  int aoff[4], boff[4];
  #pragma unroll
  for (int i = 0; i < 4; ++i) {
    int ra = wm + i * 16 + (lane & 15);
    aoff[i] = (ra * 4 + ((lane >> 4) ^ ((ra >> 1) & 3))) * 8;
    int rb = wn + i * 16 + (lane & 15);
    boff[i] = (rb * 4 + ((lane >> 4) ^ ((rb >> 1) & 3))) * 8;
  }

  for (int k0 = 0; k0 < K; k0 += 32) {
    __syncthreads();
    gld_lds16(Ab + ga0 + k0, As + s0 * 8);
    gld_lds16(Ab + ga1 + k0, As + s1 * 8);
    gld_lds16(Bb + ga0 + k0, Bs + s0 * 8);
    gld_lds16(Bb + ga1 + k0, Bs + s1 * 8);
    __syncthreads();

    short8 af[4], bfr[4];
    #pragma unroll
    for (int i = 0; i < 4; ++i) {
      af[i]  = *(const short8*)(As + aoff[i]);
      bfr[i] = *(const short8*)(Bs + boff[i]);
    }
    #pragma unroll
    for (int i = 0; i < 4; ++i)
      #pragma unroll
      for (int j = 0; j < 4; ++j)
        acc[i][j] = __builtin_amdgcn_mfma_f32_16x16x32_bf16(af[i], bfr[j], acc[i][j], 0, 0, 0);
  }

  #pragma unroll
  for (int i = 0; i < 4; ++i) {
    #pragma unroll
    for (int j = 0; j < 4; ++j) {
      const int rbase = m0 + wm + i * 16 + (lane >> 4) * 4;
      const int c = n0 + wn + j * 16 + (lane & 15);
      const float bia = bias[c];
      #pragma unroll
      for (int r = 0; r < 4; ++r) {
        float v = acc[i][j][r] + bia;
        const size_t idx = (size_t)(rbase + r) * N + c;
        if constexpr (EPI == 0) {
          ((unsigned short*)Cout)[idx] = f2bits(v);
        } else if constexpr (EPI == 1) {
          ((float*)Cout)[idx] = v + resid[idx];
        } else if constexpr (EPI == 2) {
          v = 0.5f * v * (1.0f + erff(v * 0.70710678118654752f));
          ((unsigned short*)Cout)[idx] = f2bits(v);
        } else {
          ((float*)Cout)[idx] = v + resid[idx];
        }
      }
    }
  }
}

// ---------------- MFMA flash attention (complementary Q-tile pair per block) ----------------
// qkv: [B*T, 3072] bf16 (q|k|v, each 16 heads x 64). o: [B*T,1024] bf16.
// Grid dim3(8,32): qt0 = blockIdx.x in [0,8), bh = blockIdx.y. Each block runs
// the round-7 body twice: pass 0 -> qt = 15-qt0 (heavy), pass 1 -> qt = qt0.
// Total k-iters per block = (2(15-qt0)+2) + (2qt0+2) = 34, uniform.
__global__ __launch_bounds__(256) void attn_r8(const unsigned short* __restrict__ qkv,
                                               unsigned short* __restrict__ o)
{
  __shared__ __align__(16) unsigned short Qs[128 * 64];  // swizzled chunks
  __shared__ __align__(16) unsigned short Ks[64 * 64];   // swizzled chunks
  __shared__ __align__(16) unsigned short VT[64 * 72];   // [d][tok], pad 72
  __shared__ __align__(16) unsigned short Ps[128 * 72];  // [q][tok], pad 72 (wave-own rows)
  __shared__ __align__(16) float stat_s[128];            // alpha / l (wave-own rows)

  const int tid = threadIdx.x, lane = tid & 63, wv = tid >> 6;
  const int quad = lane >> 4, l15 = lane & 15;
  const int qt0 = blockIdx.x, bh = blockIdx.y;
  const int b = bh >> 4, h = bh & 15;
  const size_t base = (size_t)b * 2048 * 3072;
  const int qcol = h * 64, kcol = 1024 + h * 64, vcol = 2048 + h * 64;

  for (int pass = 0; pass < 2; ++pass) {
    const int qt = pass ? qt0 : 15 - qt0;
    const int q0 = qt * 128;

    __syncthreads();  // prior pass fully done with Qs/Ks/VT before restage

    // ---- stage Q (1024 slots of 16B, chunk-XOR swizzle: cp = c ^ (row&7)) ----
    #pragma unroll
    for (int p = 0; p < 4; ++p) {
      int s = tid + 256 * p;
      int r = s >> 3, cp = s & 7, c = cp ^ (r & 7);
      gld_lds16(qkv + base + (size_t)(q0 + r) * 3072 + qcol + c * 8, Qs + s * 8);
    }
    __syncthreads();

    // ---- preload Q A-frags (row = wave q-row, k = dim) ----
    short8 qa[2][2];
    #pragma unroll
    for (int i = 0; i < 2; ++i)
      #pragma unroll
      for (int ks = 0; ks < 2; ++ks) {
        int ra = wv * 32 + i * 16 + l15;
        int cp = (ks * 4 + quad) ^ (ra & 7);
        qa[i][ks] = *(const short8*)(Qs + (ra * 8 + cp) * 8);
      }

    floatx4 oacc[4][2];  // O^T accumulator: [d-tile][q-subtile]
    #pragma unroll
    for (int dt = 0; dt < 4; ++dt)
      #pragma unroll
      for (int q2 = 0; q2 < 2; ++q2)
        oacc[dt][q2] = (floatx4){0.f, 0.f, 0.f, 0.f};
    float m_i[2][4], l_i[2][4];
    #pragma unroll
    for (int i = 0; i < 2; ++i)
      #pragma unroll
      for (int r = 0; r < 4; ++r) { m_i[i][r] = -3.0e38f; l_i[i][r] = 0.0f; }

    const int nkt = 2 * qt + 2;
    for (int kt = 0; kt < nkt; ++kt) {
      const int k0 = kt * 64;
      __syncthreads();  // prev-iter readers of Ks/VT done

      { // stage K (512 slots, swizzled DMA)
        int s = tid, r = s >> 3, cp = s & 7, c = cp ^ (r & 7);
        gld_lds16(qkv + base + (size_t)(k0 + r) * 3072 + kcol + c * 8, Ks + s * 8);
        s = tid + 256; r = s >> 3; cp = s & 7; c = cp ^ (r & 7);
        gld_lds16(qkv + base + (size_t)(k0 + r) * 3072 + kcol + c * 8, Ks + s * 8);
      }
      { // stage V transposed: thread owns tok pair (2p,2p+1) x 8 dims; packed b32 writes
        int p = tid & 31, dc = tid >> 5;
        const unsigned short* v0 = qkv + base + (size_t)(k0 + 2 * p) * 3072 + vcol + dc * 8;
        uint4 u0 = *(const uint4*)v0;
        uint4 u1 = *(const uint4*)(v0 + 3072);
        unsigned short* dst = VT + (size_t)(dc * 8) * 72 + 2 * p;
        *(unsigned int*)(dst + 0 * 72) = (u0.x & 0xffffu) | (u1.x << 16);
        *(unsigned int*)(dst + 1 * 72) = (u0.x >> 16)     | (u1.x & 0xffff0000u);
        *(unsigned int*)(dst + 2 * 72) = (u0.y & 0xffffu) | (u1.y << 16);
        *(unsigned int*)(dst + 3 * 72) = (u0.y >> 16)     | (u1.y & 0xffff0000u);
        *(unsigned int*)(dst + 4 * 72) = (u0.z & 0xffffu) | (u1.z << 16);
        *(unsigned int*)(dst + 5 * 72) = (u0.z >> 16)     | (u1.z & 0xffff0000u);
        *(unsigned int*)(dst + 6 * 72) = (u0.w & 0xffffu) | (u1.w << 16);
        *(unsigned int*)(dst + 7 * 72) = (u0.w >> 16)     | (u1.w & 0xffff0000u);
      }
      __syncthreads();  // staging visible (drains DMA vmcnt too)

      // ---- S = Q K^T ----
      short8 kb[4][2];
      #pragma unroll
      for (int j = 0; j < 4; ++j)
        #pragma unroll
        for (int ks = 0; ks < 2; ++ks) {
          int rb = j * 16 + l15;
          int cp = (ks * 4 + quad) ^ (rb & 7);
          kb[j][ks] = *(const short8*)(Ks + (rb * 8 + cp) * 8);
        }
      floatx4 s_[2][4];
      #pragma unroll
      for (int i = 0; i < 2; ++i)
        #pragma unroll
        for (int j = 0; j < 4; ++j)
          s_[i][j] = (floatx4){0.f, 0.f, 0.f, 0.f};
      #pragma unroll
      for (int i = 0; i < 2; ++i)
        #pragma unroll
        for (int j = 0; j < 4; ++j)
          #pragma unroll
          for (int ks = 0; ks < 2; ++ks)
            s_[i][j] = __builtin_amdgcn_mfma_f32_16x16x32_bf16(qa[i][ks], kb[j][ks], s_[i][j], 0, 0, 0);

      // ---- mask + online softmax (registers) + P write ----
      #pragma unroll
      for (int i = 0; i < 2; ++i) {
        const int rowmin = q0 + wv * 32 + i * 16;
        const int rowb = rowmin + quad * 4;
        if (k0 + 63 > rowmin) {  // diagonal tile: causal mask
          #pragma unroll
          for (int j = 0; j < 4; ++j) {
            const int col = k0 + j * 16 + l15;
            #pragma unroll
            for (int r = 0; r < 4; ++r)
              if (col > rowb + r) s_[i][j][r] = -3.0e38f;
          }
        }
        float fm[4], al[4], rs[4];
        #pragma unroll
        for (int r = 0; r < 4; ++r)
          fm[r] = fmaxf(fmaxf(s_[i][0][r], s_[i][1][r]), fmaxf(s_[i][2][r], s_[i][3][r]));
        #pragma unroll
        for (int msk = 1; msk < 16; msk <<= 1)
          #pragma unroll
          for (int r = 0; r < 4; ++r)
            fm[r] = fmaxf(fm[r], __shfl_xor(fm[r], msk, 64));
        #pragma unroll
        for (int r = 0; r < 4; ++r) {
          const float mn = fmaxf(m_i[i][r], fm[r]);
          al[r] = __expf(m_i[i][r] - mn);
          m_i[i][r] = mn;
        }
        #pragma unroll
        for (int j = 0; j < 4; ++j)
          #pragma unroll
          for (int r = 0; r < 4; ++r)
            s_[i][j][r] = __expf(s_[i][j][r] - m_i[i][r]);
        #pragma unroll
        for (int r = 0; r < 4; ++r)
          rs[r] = (s_[i][0][r] + s_[i][1][r]) + (s_[i][2][r] + s_[i][3][r]);
        #pragma unroll
        for (int msk = 1; msk < 16; msk <<= 1)
          #pragma unroll
          for (int r = 0; r < 4; ++r)
            rs[r] += __shfl_xor(rs[r], msk, 64);
        #pragma unroll
        for (int r = 0; r < 4; ++r)
          l_i[i][r] = l_i[i][r] * al[r] + rs[r];
        if (l15 == 0) {  // publish alpha (wave-own rows; same-wave read below)
          float4 a4 = { al[0], al[1], al[2], al[3] };
          *(float4*)(stat_s + wv * 32 + i * 16 + quad * 4) = a4;
        }
        #pragma unroll
        for (int j = 0; j < 4; ++j)
          #pragma unroll
          for (int r = 0; r < 4; ++r)
            Ps[(size_t)(wv * 32 + i * 16 + quad * 4 + r) * 72 + j * 16 + l15] = f2bits(s_[i][j][r]);
      }

      // ---- O^T += V^T P^T (all wave-local LDS; no extra barrier) ----
      float alq[2];
      #pragma unroll
      for (int q2 = 0; q2 < 2; ++q2)
        alq[q2] = stat_s[wv * 32 + q2 * 16 + l15];
      #pragma unroll
      for (int dt = 0; dt < 4; ++dt)
        #pragma unroll
        for (int q2 = 0; q2 < 2; ++q2)
          #pragma unroll
          for (int r = 0; r < 4; ++r)
            oacc[dt][q2][r] *= alq[q2];

      short8 va[4][2], pb[2][2];
      #pragma unroll
      for (int dt = 0; dt < 4; ++dt)
        #pragma unroll
        for (int ks = 0; ks < 2; ++ks)
          va[dt][ks] = *(const short8*)(VT + (size_t)(dt * 16 + l15) * 72 + ks * 32 + quad * 8);
      #pragma unroll
      for (int q2 = 0; q2 < 2; ++q2)
        #pragma unroll
        for (int ks = 0; ks < 2; ++ks)
          pb[q2][ks] = *(const short8*)(Ps + (size_t)(wv * 32 + q2 * 16 + l15) * 72 + ks * 32 + quad * 8);
      #pragma unroll
      for (int dt = 0; dt < 4; ++dt)
        #pragma unroll
        for (int q2 = 0; q2 < 2; ++q2)
          #pragma unroll
          for (int ks = 0; ks < 2; ++ks)
            oacc[dt][q2] = __builtin_amdgcn_mfma_f32_16x16x32_bf16(va[dt][ks], pb[q2][ks], oacc[dt][q2], 0, 0, 0);
    }

    // ---- epilogue: O = O^T / l * 32^-1 ----
    if (l15 == 0) {
      #pragma unroll
      for (int i = 0; i < 2; ++i) {
        float4 l4 = { l_i[i][0], l_i[i][1], l_i[i][2], l_i[i][3] };
        *(float4*)(stat_s + wv * 32 + i * 16 + quad * 4) = l4;
      }
    }
    #pragma unroll
    for (int q2 = 0; q2 < 2; ++q2) {
      const float linv = 0.03125f / stat_s[wv * 32 + q2 * 16 + l15];
      const size_t row = (size_t)b * 2048 + q0 + wv * 32 + q2 * 16 + l15;
      #pragma unroll
      for (int dt = 0; dt < 4; ++dt) {
        const int col = h * 64 + dt * 16 + quad * 4;
        ushort4 o4 = { f2bits(oacc[dt][q2][0] * linv), f2bits(oacc[dt][q2][1] * linv),
                       f2bits(oacc[dt][q2][2] * linv), f2bits(oacc[dt][q2][3] * linv) };
        *(ushort4*)(o + row * 1024 + col) = o4;
      }
    }
  }
}

extern "C" void kernel_launch(void* const* d_in, const int* in_sizes, int n_in,
                              void* d_out, int out_size, void* d_ws, size_t ws_size,
                              hipStream_t stream)
{
  (void)in_sizes; (void)n_in; (void)out_size; (void)ws_size;
  const float* x      = (const float*)d_in[0];
  const float* w_attn = (const float*)d_in[1];
  const float* b_attn = (const float*)d_in[2];
  const float* w_proj = (const float*)d_in[3];
  const float* b_proj = (const float*)d_in[4];
  const float* w_fc1  = (const float*)d_in[5];
  const float* b_fc1  = (const float*)d_in[6];
  const float* w_fc2  = (const float*)d_in[7];
  const float* b_fc2  = (const float*)d_in[8];
  const float* g1     = (const float*)d_in[9];
  const float* g2     = (const float*)d_in[10];
  float* out = (float*)d_out;

  // ws layout (88 MB): h/ov bf16 @0 (8MB), qkv bf16 @8MB (24MB, h2 reuses 8..16MB),
  //                    x1 f32 @32MB (16MB), h3 bf16 @48MB (32MB), WT scratch @80MB (8MB)
  char* ws = (char*)d_ws;
  unsigned short* h   = (unsigned short*)(ws);
  unsigned short* qkv = (unsigned short*)(ws + ((size_t)8  << 20));
  unsigned short* ov  = (unsigned short*)(ws);                       // reuse h
  float*          x1  = (float*)         (ws + ((size_t)32 << 20));
  unsigned short* h2  = (unsigned short*)(ws + ((size_t)8  << 20));  // reuse qkv
  unsigned short* h3  = (unsigned short*)(ws + ((size_t)48 << 20));
  unsigned short* WT  = (unsigned short*)(ws + ((size_t)80 << 20));

  const int M = 4096;

  rmsnorm_r8<<<M, 256, 0, stream>>>(x, g1, h);
  wprep_r8<<<dim3(3072 / 32, 1024 / 32), 256, 0, stream>>>(w_attn, WT, 1024, 3072);
  gemm_r8<0><<<dim3(3072 / 128, M / 128), 256, 0, stream>>>(h, WT, b_attn, nullptr, qkv, M, 3072, 1024);
  attn_r8<<<dim3(8, 32), 256, 0, stream>>>(qkv, ov);
  wprep_r8<<<dim3(1024 / 32, 1024 / 32), 256, 0, stream>>>(w_proj, WT, 1024, 1024);
  gemm_r8<1><<<dim3(1024 / 128, M / 128), 256, 0, stream>>>(ov, WT, b_proj, x, x1, M, 1024, 1024);
  rmsnorm_r8<<<M, 256, 0, stream>>>(x1, g2, h2);
  wprep_r8<<<dim3(4096 / 32, 1024 / 32), 256, 0, stream>>>(w_fc1, WT, 1024, 4096);
  gemm_r8<2><<<dim3(4096 / 128, M / 128), 256, 0, stream>>>(h2, WT, b_fc1, nullptr, h3, M, 4096, 1024);
  wprep_r8<<<dim3(1024 / 32, 4096 / 32), 256, 0, stream>>>(w_fc2, WT, 4096, 1024);
  gemm_r8<3><<<dim3(1024 / 128, M / 128), 256, 0, stream>>>(h3, WT, b_fc2, x1, out, M, 1024, 4096);
}